// Round 9
// baseline (190.746 us; speedup 1.0000x reference)
//
#include <hip/hip_runtime.h>

#define D 256
#define F4_PER_ROW (D / 4)  // 64 float4 per row

typedef float fx4 __attribute__((ext_vector_type(4)));  // native vec for nontemporal builtin

__device__ __forceinline__ float dot4(float4 a, float4 b) {
    return fmaf(a.x, b.x, fmaf(a.y, b.y, fmaf(a.z, b.z, a.w * b.w)));
}

__device__ __forceinline__ void nt_store4(float4 v, float4* p) {
    fx4 t; t.x = v.x; t.y = v.y; t.z = v.z; t.w = v.w;
    __builtin_nontemporal_store(t, reinterpret_cast<fx4*>(p));
}

// 4 rows per wave: 16 lanes/row, 4 float4 (16 floats) per lane per input.
// 16 load instructions per wave = 16KB in flight (2x round 8) to raise the
// per-CU outstanding-bytes duty cycle. One-shot; butterfly is 4 levels
// within each 16-lane group. Native rsq/rcp/exp2 epilogue.
__global__ __launch_bounds__(1024) void merge_xs_kernel(
    const float* __restrict__ x0, const float* __restrict__ x1,
    const float* __restrict__ x2, const float* __restrict__ x3,
    const float* __restrict__ w_att, const float* __restrict__ b_att,
    float* __restrict__ emb, float* __restrict__ sc_out, int N)
{
    const int lane = threadIdx.x & 63;
    const int sub  = lane & 15;       // lane within the row's 16-lane group
    const int grp  = lane >> 4;       // which of the wave's 4 rows (0..3)
    const int wid  = threadIdx.x >> 6;
    const int wpb  = blockDim.x >> 6;

    const int nUnits = (N + 3) >> 2;  // 4-row units
    const int unit = blockIdx.x * wpb + wid;
    if (unit >= nUnits) return;

    const int row = unit * 4 + grp;
    const bool valid = row < N;
    const size_t base = valid ? ((size_t)row * F4_PER_ROW + sub) : (size_t)sub;

    const float4* x0f = reinterpret_cast<const float4*>(x0);
    const float4* x1f = reinterpret_cast<const float4*>(x1);
    const float4* x2f = reinterpret_cast<const float4*>(x2);
    const float4* x3f = reinterpret_cast<const float4*>(x3);
    float4* embf      = reinterpret_cast<float4*>(emb);

    // Input loads first — 16 dwordx4 in flight immediately.
    float4 v0a = x0f[base], v0b = x0f[base + 16], v0c = x0f[base + 32], v0d = x0f[base + 48];
    float4 v1a = x1f[base], v1b = x1f[base + 16], v1c = x1f[base + 32], v1d = x1f[base + 48];
    float4 v2a = x2f[base], v2b = x2f[base + 16], v2c = x2f[base + 32], v2d = x2f[base + 48];
    float4 v3a = x3f[base], v3b = x3f[base + 16], v3c = x3f[base + 32], v3d = x3f[base + 48];

    // Weight slices for this lane's 4 chunks (L1/L2-resident).
    const float4* wmf = reinterpret_cast<const float4*>(w_att);  // w_att[0:256]
    const float4* wqf = wmf + 64;                                // w_att[256:512]
    const float4 wma = wmf[sub], wmb = wmf[sub + 16], wmc = wmf[sub + 32], wmd = wmf[sub + 48];
    const float4 wqa = wqf[sub], wqb = wqf[sub + 16], wqc = wqf[sub + 32], wqd = wqf[sub + 48];
    const float b = b_att[0];

    // 8 per-lane partials: ||x||^2 and weight-dot for each input.
    float r0 = dot4(v0a, v0a) + dot4(v0b, v0b) + dot4(v0c, v0c) + dot4(v0d, v0d);
    float r1 = dot4(v0a, wqa) + dot4(v0b, wqb) + dot4(v0c, wqc) + dot4(v0d, wqd);
    float r2 = dot4(v1a, v1a) + dot4(v1b, v1b) + dot4(v1c, v1c) + dot4(v1d, v1d);
    float r3 = dot4(v1a, wma) + dot4(v1b, wmb) + dot4(v1c, wmc) + dot4(v1d, wmd);
    float r4 = dot4(v2a, v2a) + dot4(v2b, v2b) + dot4(v2c, v2c) + dot4(v2d, v2d);
    float r5 = dot4(v2a, wma) + dot4(v2b, wmb) + dot4(v2c, wmc) + dot4(v2d, wmd);
    float r6 = dot4(v3a, v3a) + dot4(v3b, v3b) + dot4(v3c, v3c) + dot4(v3d, v3d);
    float r7 = dot4(v3a, wma) + dot4(v3b, wmb) + dot4(v3c, wmc) + dot4(v3d, wmd);

    // Butterfly over 16 lanes (offsets < 16 stay within each group).
    #pragma unroll
    for (int off = 8; off > 0; off >>= 1) {
        r0 += __shfl_xor(r0, off, 64);
        r1 += __shfl_xor(r1, off, 64);
        r2 += __shfl_xor(r2, off, 64);
        r3 += __shfl_xor(r3, off, 64);
        r4 += __shfl_xor(r4, off, 64);
        r5 += __shfl_xor(r5, off, 64);
        r6 += __shfl_xor(r6, off, 64);
        r7 += __shfl_xor(r7, off, 64);
    }

    // 1/||x|| directly via v_rsq_f32 (clamp matches eps=1e-12 on the norm).
    const float in0 = __builtin_amdgcn_rsqf(fmaxf(r0, 1e-24f));
    const float in1 = __builtin_amdgcn_rsqf(fmaxf(r2, 1e-24f));
    const float in2 = __builtin_amdgcn_rsqf(fmaxf(r4, 1e-24f));
    const float in3 = __builtin_amdgcn_rsqf(fmaxf(r6, 1e-24f));

    const float qterm = fmaf(r1, in0, b);
    float s1 = fmaf(r3, in1, qterm);
    float s2 = fmaf(r5, in2, qterm);
    float s3 = fmaf(r7, in3, qterm);

    // leaky_relu(0.01)
    s1 = s1 > 0.f ? s1 : 0.01f * s1;
    s2 = s2 > 0.f ? s2 : 0.01f * s2;
    s3 = s3 > 0.f ? s3 : 0.01f * s3;

    // softmax over the 3 messages — native exp2/rcp.
    const float m  = fmaxf(s1, fmaxf(s2, s3));
    const float LOG2E = 1.4426950408889634f;
    const float e1 = __builtin_amdgcn_exp2f((s1 - m) * LOG2E);
    const float e2 = __builtin_amdgcn_exp2f((s2 - m) * LOG2E);
    const float e3 = __builtin_amdgcn_exp2f((s3 - m) * LOG2E);
    const float inv = __builtin_amdgcn_rcpf(e1 + e2 + e3);
    const float sc1 = e1 * inv, sc2 = e2 * inv, sc3 = e3 * inv;

    // embedding = x0 + sum_l (sc_l / ||x_l||) * x_l
    const float c1 = sc1 * in1, c2 = sc2 * in2, c3 = sc3 * in3;
    float4 oa, ob, oc, od;
    oa.x = fmaf(c1, v1a.x, fmaf(c2, v2a.x, fmaf(c3, v3a.x, v0a.x)));
    oa.y = fmaf(c1, v1a.y, fmaf(c2, v2a.y, fmaf(c3, v3a.y, v0a.y)));
    oa.z = fmaf(c1, v1a.z, fmaf(c2, v2a.z, fmaf(c3, v3a.z, v0a.z)));
    oa.w = fmaf(c1, v1a.w, fmaf(c2, v2a.w, fmaf(c3, v3a.w, v0a.w)));
    ob.x = fmaf(c1, v1b.x, fmaf(c2, v2b.x, fmaf(c3, v3b.x, v0b.x)));
    ob.y = fmaf(c1, v1b.y, fmaf(c2, v2b.y, fmaf(c3, v3b.y, v0b.y)));
    ob.z = fmaf(c1, v1b.z, fmaf(c2, v2b.z, fmaf(c3, v3b.z, v0b.z)));
    ob.w = fmaf(c1, v1b.w, fmaf(c2, v2b.w, fmaf(c3, v3b.w, v0b.w)));
    oc.x = fmaf(c1, v1c.x, fmaf(c2, v2c.x, fmaf(c3, v3c.x, v0c.x)));
    oc.y = fmaf(c1, v1c.y, fmaf(c2, v2c.y, fmaf(c3, v3c.y, v0c.y)));
    oc.z = fmaf(c1, v1c.z, fmaf(c2, v2c.z, fmaf(c3, v3c.z, v0c.z)));
    oc.w = fmaf(c1, v1c.w, fmaf(c2, v2c.w, fmaf(c3, v3c.w, v0c.w)));
    od.x = fmaf(c1, v1d.x, fmaf(c2, v2d.x, fmaf(c3, v3d.x, v0d.x)));
    od.y = fmaf(c1, v1d.y, fmaf(c2, v2d.y, fmaf(c3, v3d.y, v0d.y)));
    od.z = fmaf(c1, v1d.z, fmaf(c2, v2d.z, fmaf(c3, v3d.z, v0d.z)));
    od.w = fmaf(c1, v1d.w, fmaf(c2, v2d.w, fmaf(c3, v3d.w, v0d.w)));

    if (valid) {
        nt_store4(oa, &embf[base]);
        nt_store4(ob, &embf[base + 16]);
        nt_store4(oc, &embf[base + 32]);
        nt_store4(od, &embf[base + 48]);
        if (sub == 0) {
            __builtin_nontemporal_store(sc1, &sc_out[row]);
            __builtin_nontemporal_store(sc2, &sc_out[N + row]);
            __builtin_nontemporal_store(sc3, &sc_out[2 * N + row]);
        }
    }
}

extern "C" void kernel_launch(void* const* d_in, const int* in_sizes, int n_in,
                              void* d_out, int out_size, void* d_ws, size_t ws_size,
                              hipStream_t stream) {
    const float* x0    = (const float*)d_in[0];
    const float* x1    = (const float*)d_in[1];
    const float* x2    = (const float*)d_in[2];
    const float* x3    = (const float*)d_in[3];
    const float* w_att = (const float*)d_in[4];
    const float* b_att = (const float*)d_in[5];

    const int N = in_sizes[0] / D;  // 200000
    float* emb = (float*)d_out;
    float* sc  = emb + (size_t)N * D;

    const int threads = 1024;               // 16 waves/block, 4 rows/wave
    const int wpb = threads / 64;
    const int nUnits = (N + 3) / 4;         // 50000
    const int blocks = (nUnits + wpb - 1) / wpb;  // 3125 — one unit per wave

    merge_xs_kernel<<<blocks, threads, 0, stream>>>(x0, x1, x2, x3, w_att, b_att,
                                                    emb, sc, N);
}

// Round 10
// 189.430 us; speedup vs baseline: 1.0069x; 1.0069x over previous
//
#include <hip/hip_runtime.h>

#define D 256
#define F4_PER_ROW (D / 4)  // 64 float4 per row

typedef float fx4 __attribute__((ext_vector_type(4)));  // native vec for nontemporal builtin

__device__ __forceinline__ float dot4(float4 a, float4 b) {
    return fmaf(a.x, b.x, fmaf(a.y, b.y, fmaf(a.z, b.z, a.w * b.w)));
}

__device__ __forceinline__ void nt_store4(float4 v, float4* p) {
    fx4 t; t.x = v.x; t.y = v.y; t.z = v.z; t.w = v.w;
    __builtin_nontemporal_store(t, reinterpret_cast<fx4*>(p));
}

// Best-of-plateau: R4 geometry (2 rows/wave, 32 lanes/row, 256-thread blocks,
// one-shot — one unit per wave, TLP hides latency) + R8 native-math epilogue
// (rsq/rcp/exp2). Delivered BW ~5.5 TB/s = ~88% of the 6.3 TB/s copy ceiling;
// traffic (1.027 GB) is irreducible, so this is the plateau configuration.
__global__ __launch_bounds__(256) void merge_xs_kernel(
    const float* __restrict__ x0, const float* __restrict__ x1,
    const float* __restrict__ x2, const float* __restrict__ x3,
    const float* __restrict__ w_att, const float* __restrict__ b_att,
    float* __restrict__ emb, float* __restrict__ sc_out, int N)
{
    const int lane = threadIdx.x & 63;
    const int sub  = lane & 31;       // lane within the row's 32-lane group
    const int half = lane >> 5;       // which of the wave's 2 rows
    const int wid  = threadIdx.x >> 6;
    const int wpb  = blockDim.x >> 6;

    const int nUnits = (N + 1) >> 1;
    const int unit = blockIdx.x * wpb + wid;
    if (unit >= nUnits) return;

    const int row = unit * 2 + half;
    const bool valid = row < N;
    const size_t base = valid ? ((size_t)row * F4_PER_ROW + sub) : (size_t)sub;

    const float4* x0f = reinterpret_cast<const float4*>(x0);
    const float4* x1f = reinterpret_cast<const float4*>(x1);
    const float4* x2f = reinterpret_cast<const float4*>(x2);
    const float4* x3f = reinterpret_cast<const float4*>(x3);
    float4* embf      = reinterpret_cast<float4*>(emb);

    // Input loads first — get them in flight immediately.
    float4 v0a = x0f[base], v0b = x0f[base + 32];
    float4 v1a = x1f[base], v1b = x1f[base + 32];
    float4 v2a = x2f[base], v2b = x2f[base + 32];
    float4 v3a = x3f[base], v3b = x3f[base + 32];

    // Weight slices (L1/L2-resident).
    const float4* wmf = reinterpret_cast<const float4*>(w_att);  // w_att[0:256]
    const float4* wqf = wmf + 64;                                // w_att[256:512]
    const float4 wma = wmf[sub], wmb = wmf[sub + 32];
    const float4 wqa = wqf[sub], wqb = wqf[sub + 32];
    const float b = b_att[0];

    // 8 per-lane partials: ||x||^2 and weight-dot for each input.
    float r0 = dot4(v0a, v0a) + dot4(v0b, v0b);
    float r1 = dot4(v0a, wqa) + dot4(v0b, wqb);
    float r2 = dot4(v1a, v1a) + dot4(v1b, v1b);
    float r3 = dot4(v1a, wma) + dot4(v1b, wmb);
    float r4 = dot4(v2a, v2a) + dot4(v2b, v2b);
    float r5 = dot4(v2a, wma) + dot4(v2b, wmb);
    float r6 = dot4(v3a, v3a) + dot4(v3b, v3b);
    float r7 = dot4(v3a, wma) + dot4(v3b, wmb);

    // Butterfly over 32 lanes (offsets < 32 stay within each half-wave).
    #pragma unroll
    for (int off = 16; off > 0; off >>= 1) {
        r0 += __shfl_xor(r0, off, 64);
        r1 += __shfl_xor(r1, off, 64);
        r2 += __shfl_xor(r2, off, 64);
        r3 += __shfl_xor(r3, off, 64);
        r4 += __shfl_xor(r4, off, 64);
        r5 += __shfl_xor(r5, off, 64);
        r6 += __shfl_xor(r6, off, 64);
        r7 += __shfl_xor(r7, off, 64);
    }

    // 1/||x|| directly via v_rsq_f32 (clamp matches eps=1e-12 on the norm).
    const float in0 = __builtin_amdgcn_rsqf(fmaxf(r0, 1e-24f));
    const float in1 = __builtin_amdgcn_rsqf(fmaxf(r2, 1e-24f));
    const float in2 = __builtin_amdgcn_rsqf(fmaxf(r4, 1e-24f));
    const float in3 = __builtin_amdgcn_rsqf(fmaxf(r6, 1e-24f));

    const float qterm = fmaf(r1, in0, b);
    float s1 = fmaf(r3, in1, qterm);
    float s2 = fmaf(r5, in2, qterm);
    float s3 = fmaf(r7, in3, qterm);

    // leaky_relu(0.01)
    s1 = s1 > 0.f ? s1 : 0.01f * s1;
    s2 = s2 > 0.f ? s2 : 0.01f * s2;
    s3 = s3 > 0.f ? s3 : 0.01f * s3;

    // softmax over the 3 messages — native exp2/rcp.
    const float m  = fmaxf(s1, fmaxf(s2, s3));
    const float LOG2E = 1.4426950408889634f;
    const float e1 = __builtin_amdgcn_exp2f((s1 - m) * LOG2E);
    const float e2 = __builtin_amdgcn_exp2f((s2 - m) * LOG2E);
    const float e3 = __builtin_amdgcn_exp2f((s3 - m) * LOG2E);
    const float inv = __builtin_amdgcn_rcpf(e1 + e2 + e3);
    const float sc1 = e1 * inv, sc2 = e2 * inv, sc3 = e3 * inv;

    // embedding = x0 + sum_l (sc_l / ||x_l||) * x_l
    const float c1 = sc1 * in1, c2 = sc2 * in2, c3 = sc3 * in3;
    float4 oa, ob;
    oa.x = fmaf(c1, v1a.x, fmaf(c2, v2a.x, fmaf(c3, v3a.x, v0a.x)));
    oa.y = fmaf(c1, v1a.y, fmaf(c2, v2a.y, fmaf(c3, v3a.y, v0a.y)));
    oa.z = fmaf(c1, v1a.z, fmaf(c2, v2a.z, fmaf(c3, v3a.z, v0a.z)));
    oa.w = fmaf(c1, v1a.w, fmaf(c2, v2a.w, fmaf(c3, v3a.w, v0a.w)));
    ob.x = fmaf(c1, v1b.x, fmaf(c2, v2b.x, fmaf(c3, v3b.x, v0b.x)));
    ob.y = fmaf(c1, v1b.y, fmaf(c2, v2b.y, fmaf(c3, v3b.y, v0b.y)));
    ob.z = fmaf(c1, v1b.z, fmaf(c2, v2b.z, fmaf(c3, v3b.z, v0b.z)));
    ob.w = fmaf(c1, v1b.w, fmaf(c2, v2b.w, fmaf(c3, v3b.w, v0b.w)));

    if (valid) {
        nt_store4(oa, &embf[base]);
        nt_store4(ob, &embf[base + 32]);
        if (sub == 0) {
            __builtin_nontemporal_store(sc1, &sc_out[row]);
            __builtin_nontemporal_store(sc2, &sc_out[N + row]);
            __builtin_nontemporal_store(sc3, &sc_out[2 * N + row]);
        }
    }
}

extern "C" void kernel_launch(void* const* d_in, const int* in_sizes, int n_in,
                              void* d_out, int out_size, void* d_ws, size_t ws_size,
                              hipStream_t stream) {
    const float* x0    = (const float*)d_in[0];
    const float* x1    = (const float*)d_in[1];
    const float* x2    = (const float*)d_in[2];
    const float* x3    = (const float*)d_in[3];
    const float* w_att = (const float*)d_in[4];
    const float* b_att = (const float*)d_in[5];

    const int N = in_sizes[0] / D;  // 200000
    float* emb = (float*)d_out;
    float* sc  = emb + (size_t)N * D;

    const int threads = 256;                // 4 waves/block, 2 rows/wave
    const int wpb = threads / 64;
    const int nUnits = (N + 1) / 2;         // 100000
    const int blocks = (nUnits + wpb - 1) / wpb;  // 25000 — one unit per wave

    merge_xs_kernel<<<blocks, threads, 0, stream>>>(x0, x1, x2, x3, w_att, b_att,
                                                    emb, sc, N);
}